// Round 8
// baseline (303.261 us; speedup 1.0000x reference)
//
#include <hip/hip_runtime.h>
#include <cfloat>

#define BB 2
#define NN 8192
#define OO 64
#define KK 20
#define QB 128        // queries per kS block (4 waves x 32)
#define MS 16         // point splits in kS (2048 blocks -> 8 blocks/CU by resources)
#define CHUNK 512     // points per kS split (128 KB, L2-pinned, 2 chunks/XCD)
#define CAPQ 192      // candidate slots per query (tight thr: mean ~80)
#define RB 8          // kS per-lane buffer depth
#define RBS 9         // lbuf stride in u64; ODD stride -> conflict-free

using f16x8  = __attribute__((ext_vector_type(8))) _Float16;
using f32x16 = __attribute__((ext_vector_type(16))) float;
typedef unsigned long long u64;

// ws layout (float units)
#define XH_OFF ((size_t)0)
#define XL_OFF (XH_OFF + (size_t)BB*NN*32)
#define SQ_OFF (XL_OFF + (size_t)BB*NN*32)        // B*N
#define Y1_OFF (SQ_OFF + (size_t)BB*NN)           // B*N*64 (n-major rows)
#define Y2_OFF (Y1_OFF + (size_t)BB*NN*64)        // B*N*64 (n-major rows)
#define TH_OFF (Y2_OFF + (size_t)BB*NN*64)        // B*N thresholds (float)
#define CN_OFF (TH_OFF + (size_t)BB*NN)           // B*N counters (int)
#define TL_OFF (CN_OFF + (size_t)BB*NN)           // 2*B*N*KK half-sample top-20 lists
#define CA_OFF (TL_OFF + (size_t)2*BB*NN*KK)      // B*N*CAPQ u64
#define IX_OFF (CA_OFF + (size_t)BB*NN*CAPQ*2)    // B*N*K (int)
#define HX_OFF (IX_OFF + (size_t)BB*NN*KK)        // B*64*N (o-major)
#define HN_OFF (HX_OFF + (size_t)BB*NN*64)        // B*64*N (o-major)
#define ST_OFF (HN_OFF + (size_t)BB*NN*64)        // 128

// MFMA-native swizzled fragment layout (verified r6-18)
__device__ __forceinline__ size_t frag_off(int b, int tile, int t, int lane) {
    return ((((size_t)b * (NN / 32) + tile) * 4 + t) * 64 + lane) * 8;
}

// order-preserving float->uint map (works for negatives too)
__device__ __forceinline__ unsigned fmap(float f) {
    unsigned u = __float_as_uint(f);
    return (u & 0x80000000u) ? ~u : (u | 0x80000000u);
}

// ---------- branchless selection primitives ----------
__device__ __forceinline__ void sort16(float* v) {      // bitonic, ascending
#pragma unroll
    for (int k = 2; k <= 16; k <<= 1) {
#pragma unroll
        for (int j = k >> 1; j > 0; j >>= 1) {
#pragma unroll
            for (int i = 0; i < 16; ++i) {
                int l = i ^ j;
                if (l > i) {
                    bool up = ((i & k) == 0);
                    float mn = fminf(v[i], v[l]);
                    float mx = fmaxf(v[i], v[l]);
                    v[i] = up ? mn : mx;
                    v[l] = up ? mx : mn;
                }
            }
        }
    }
}
__device__ __forceinline__ void bmerge32(float* A) {    // bitonic input -> ascending
#pragma unroll
    for (int j = 16; j > 0; j >>= 1) {
#pragma unroll
        for (int i = 0; i < 32; ++i) {
            if ((i & j) == 0) {
                float mn = fminf(A[i], A[i | j]);
                float mx = fmaxf(A[i], A[i | j]);
                A[i] = mn;
                A[i | j] = mx;
            }
        }
    }
}
// A(32, asc) <- 32 smallest of A U B(16, asc)
__device__ __forceinline__ void merge32_16(float* A, const float* B) {
#pragma unroll
    for (int i = 16; i < 32; ++i) A[i] = fminf(A[i], B[31 - i]);
    bmerge32(A);
}
// A(32, asc) <- 32 smallest of A U B(32, asc)
__device__ __forceinline__ void merge32_32(float* A, const float* B) {
    float t[32];
#pragma unroll
    for (int i = 0; i < 32; ++i) t[i] = fminf(A[i], B[31 - i]);
    bmerge32(t);
#pragma unroll
    for (int i = 0; i < 32; ++i) A[i] = t[i];
}

// ---------- distance tile pieces: 32 points x 32 queries, hi/lo fp16 MFMA ----------
// C: col=lane&31 (query), row = (i&3) + 8*(i>>2) + 4*kh.  Verified rounds 3-18.
__device__ __forceinline__ void load_atile(const _Float16* __restrict__ xh,
                                           const _Float16* __restrict__ xl,
                                           int b, int ptile, int lane,
                                           f16x8* Ah, f16x8* Al) {
#pragma unroll
    for (int t = 0; t < 4; ++t) {
        size_t o = frag_off(b, ptile, t, lane);
        Ah[t] = *(const f16x8*)&xh[o];   // coalesced: 64 lanes x 16 B contiguous
        Al[t] = *(const f16x8*)&xl[o];
    }
}

// r22: sqs holds -sq/2 (pre-scaled at staging). c0 is INITIALIZED from sqs, so the
// MFMA chain computes -sq/2 + dot_hi directly. Shared by kT and kS -> d stays
// bitwise-identical across both kernels (the kM2 threshold invariant).
__device__ __forceinline__ void dist_from_frags(const f16x8* Ah, const f16x8* Al,
                                                const float* sqs, int sbase, int kh,
                                                const f16x8* Qh, const f16x8* Ql,
                                                float* dv) {
    f32x16 c0, c1;
#pragma unroll
    for (int r2 = 0; r2 < 4; ++r2) {
        float4 sv = *(const float4*)&sqs[sbase + 8 * r2 + 4 * kh];  // -sq/2, LDS broadcast
        c0[4 * r2 + 0] = sv.x;
        c0[4 * r2 + 1] = sv.y;
        c0[4 * r2 + 2] = sv.z;
        c0[4 * r2 + 3] = sv.w;
    }
#pragma unroll
    for (int i = 0; i < 16; ++i) c1[i] = 0.f;
#pragma unroll
    for (int t = 0; t < 4; ++t) {
        c0 = __builtin_amdgcn_mfma_f32_32x32x16_f16(Ah[t], Qh[t], c0, 0, 0, 0); // -sq/2 + hi*hi
        c1 = __builtin_amdgcn_mfma_f32_32x32x16_f16(Ah[t], Ql[t], c1, 0, 0, 0); // hi*lo
        c1 = __builtin_amdgcn_mfma_f32_32x32x16_f16(Al[t], Qh[t], c1, 0, 0, 0); // lo*hi
    }
#pragma unroll
    for (int i = 0; i < 16; ++i)
        dv[i] = fmaf(-2.f, c0[i], -9.765625e-4f * c1[i]);  // d = sq - 2dot - cross
}

__device__ __forceinline__ void load_qfrag(const _Float16* __restrict__ xh,
                                           const _Float16* __restrict__ xl,
                                           int b, int qbase, int lane,
                                           f16x8* Qh, f16x8* Ql) {
    const int qtile = qbase >> 5;
#pragma unroll
    for (int t = 0; t < 4; ++t) {
        size_t o = frag_off(b, qtile, t, lane);
        Qh[t] = *(const f16x8*)&xh[o];
        Ql[t] = *(const f16x8*)&xl[o];
    }
}

// ---------------- kernel A: sq + fp16 hi/lo split (swizzled) + y1/y2 ----------------
// r17 structure: x staged in LDS once; o-split into 2 groups of 32.
__global__ void __launch_bounds__(256, 2)
kA(const float* __restrict__ x, const float* __restrict__ W,
   float* __restrict__ ws) {
    __shared__ __align__(16) float w1s[32 * 64];   // 8 KB: this block's 32 o rows
    __shared__ __align__(16) float w2s[32 * 64];   // 8 KB
    __shared__ float xs[64 * 65];                  // 16.6 KB [c][n], pad 65
    __shared__ float tb[64 * 33];                  // 8.4 KB transpose, pad 33
    const int bb = blockIdx.z;
    const int og = blockIdx.y;        // o-group: 0 or 1
    const int obase = og * 32;
    const int nbase = blockIdx.x * 64;
    const int tn = threadIdx.x & 63, tq = threadIdx.x >> 6;

    // W slice (32 o x 64 c), w2 = W_right - W_left
    for (int i = threadIdx.x; i < 2048; i += 256) {
        int ol = i >> 6, c = i & 63;
        float a = W[(obase + ol) * 128 + c];
        float d = W[(obase + ol) * 128 + 64 + c];
        w1s[i] = a;
        w2s[i] = d - a;
    }
    // x tile: [c][n] staged coalesced (256 B per row-segment)
    for (int i = threadIdx.x; i < 4096; i += 256) {
        int c = i >> 6, nl = i & 63;
        xs[c * 65 + nl] = x[((size_t)bb * 64 + c) * NN + nbase + nl];
    }
    if (og == 0) {
        if (blockIdx.x == 0 && bb == 0 && threadIdx.x < 128)
            ws[ST_OFF + threadIdx.x] = 0.f;   // zero stats accumulators (pre-kC1)
        int gid = (bb * 128 + blockIdx.x) * 256 + threadIdx.x;  // init cnt (pre-kS)
        if (gid < BB * NN) ((int*)(ws + CN_OFF))[gid] = 0;
    }
    __syncthreads();

    // per-thread column n = tn (conflict-free: bank = (c+tn)%32)
    float xc[64];
#pragma unroll
    for (int c = 0; c < 64; ++c) xc[c] = xs[c * 65 + tn];

    if (og == 0 && tq == 0) {   // sq + swizzled fp16 split (one wave, per-n)
        float sqv = 0.f;
#pragma unroll
        for (int c = 0; c < 64; ++c) sqv = fmaf(xc[c], xc[c], sqv);
        int n = nbase + tn;
        ws[SQ_OFF + (size_t)bb * NN + n] = sqv;
        _Float16* xh = (_Float16*)(ws + XH_OFF);
        _Float16* xl = (_Float16*)(ws + XL_OFF);
        int tile = n >> 5, r = n & 31;
#pragma unroll
        for (int t = 0; t < 4; ++t) {
#pragma unroll
            for (int kh = 0; kh < 2; ++kh) {
                f16x8 vh, vl;
#pragma unroll
                for (int j = 0; j < 8; ++j) {
                    float v = xc[t * 16 + kh * 8 + j];
                    _Float16 h = (_Float16)v;
                    vh[j] = h;
                    vl[j] = (_Float16)((v - (float)h) * 2048.f);  // x = hi + lo*2^-11
                }
                size_t o = frag_off(bb, tile, t, kh * 32 + r);    // lane-consecutive
                *(f16x8*)&xh[o] = vh;
                *(f16x8*)&xl[o] = vl;
            }
        }
    }

    // projections: thread = n, 8 o's each (o_local = tq*8 + o2)
    float a1v[8], a2v[8];
#pragma unroll
    for (int o2 = 0; o2 < 8; ++o2) {
        int ol = tq * 8 + o2;
        const float4* w1v = (const float4*)&w1s[ol * 64];
        const float4* w2v = (const float4*)&w2s[ol * 64];
        float a1 = 0.f, a2 = 0.f;
#pragma unroll
        for (int c4 = 0; c4 < 16; ++c4) {
            float4 v1 = w1v[c4];   // broadcast ds_read_b128
            float4 v2 = w2v[c4];
            a1 = fmaf(v1.x, xc[4*c4],   a1);
            a1 = fmaf(v1.y, xc[4*c4+1], a1);
            a1 = fmaf(v1.z, xc[4*c4+2], a1);
            a1 = fmaf(v1.w, xc[4*c4+3], a1);
            a2 = fmaf(v2.x, xc[4*c4],   a2);
            a2 = fmaf(v2.y, xc[4*c4+1], a2);
            a2 = fmaf(v2.z, xc[4*c4+2], a2);
            a2 = fmaf(v2.w, xc[4*c4+3], a2);
        }
        a1v[o2] = a1;
        a2v[o2] = a2;
    }

    // y1: transpose through tb, then full-line stores (2 rows x 128 B per instr)
    const int lo = threadIdx.x & 31;          // o_local
    const int lp = (threadIdx.x >> 5) & 1;    // row parity
#pragma unroll
    for (int o2 = 0; o2 < 8; ++o2)
        tb[tn * 33 + tq * 8 + o2] = a1v[o2];
    __syncthreads();
#pragma unroll
    for (int j = 0; j < 8; ++j) {
        int r = tq * 16 + 2 * j + lp;
        ws[Y1_OFF + ((size_t)bb * NN + nbase + r) * 64 + obase + lo] = tb[r * 33 + lo];
    }
    __syncthreads();
#pragma unroll
    for (int o2 = 0; o2 < 8; ++o2)
        tb[tn * 33 + tq * 8 + o2] = a2v[o2];
    __syncthreads();
#pragma unroll
    for (int j = 0; j < 8; ++j) {
        int r = tq * 16 + 2 * j + lp;
        ws[Y2_OFF + ((size_t)bb * NN + nbase + r) * 64 + obase + lo] = tb[r * 33 + lo];
    }
}

// ---------------- kernel T (phase-0): half-sample top-20 lists, branchless networks ----------------
__global__ void __launch_bounds__(256, 3)
kT(const _Float16* __restrict__ xh, const _Float16* __restrict__ xl,
   const float* __restrict__ sq, float* __restrict__ thrL) {
    __shared__ float mrg[32 * 128];          // [j][wave*32+qc]
    __shared__ __align__(16) float sqs[1024];  // staged -sq/2 slice (lgkmcnt path)
    const int tid  = threadIdx.x;
    const int lane = tid & 63;
    const int wv   = tid >> 6;
    const int qcol = lane & 31;
    const int kh   = lane >> 5;
    const int b     = blockIdx.y >> 1;
    const int s     = blockIdx.y & 1;     // sample half
    const int qbase = blockIdx.x * 32;

    for (int i = tid; i < 1024; i += 256)
        sqs[i] = -0.5f * sq[(size_t)b * NN + s * 1024 + i];   // r22: pre-scaled

    f16x8 Qh[4], Ql[4];
    load_qfrag(xh, xl, b, qbase, lane, Qh, Ql);
    __syncthreads();

    float dk[32];
#pragma unroll
    for (int i = 0; i < 32; ++i) dk[i] = FLT_MAX;

    const int p0 = s * 1024 + wv * 256;
    for (int pt = p0; pt < p0 + 256; pt += 32) {
        f16x8 Ah[4], Al[4];
        load_atile(xh, xl, b, pt >> 5, lane, Ah, Al);
        float dv[16];
        dist_from_frags(Ah, Al, sqs, pt - s * 1024, kh, Qh, Ql, dv);
        float m16 = dv[0];
#pragma unroll
        for (int i = 1; i < 16; ++i) m16 = fminf(m16, dv[i]);
        if (__any(m16 < dk[KK - 1])) {   // wave-uniform tile skip (late tiles)
            sort16(dv);
            merge32_16(dk, dv);
        }
    }

    // kh pair merge via shfl (branchless; kh==1 lanes self-merge harmlessly)
    {
        float B[32];
#pragma unroll
        for (int j = 0; j < 32; ++j) B[j] = __shfl(dk[j], lane | 32);
        merge32_32(dk, B);
    }
    if (kh == 0) {
#pragma unroll
        for (int j = 0; j < 32; ++j) mrg[j * 128 + wv * 32 + qcol] = dk[j];
    }
    __syncthreads();

    // cross-wave merge: wave 0, lanes 0-31, one query per lane; emit sorted 20-list
    if (tid < 32) {
        float B[32];
#pragma unroll 1
        for (int w = 1; w < 4; ++w) {
#pragma unroll
            for (int j = 0; j < 32; ++j) B[j] = mrg[j * 128 + w * 32 + tid];
            merge32_32(dk, B);
        }
        size_t base = (((size_t)b * 2 + s) * NN + qbase + tid) * KK;
#pragma unroll
        for (int j = 0; j < KK; ++j) thrL[base + j] = dk[j];
    }
}

// ---------------- kernel M2: exact union 20th via k-th-of-two-sorted identity ----------------
// r18-keep: ans = min_{i} max(A[i-1], B[19-i]) -- 10 independent float4 loads.
__global__ void kM2(const float* __restrict__ thrL, float* __restrict__ thr) {
    int gid = blockIdx.x * 256 + threadIdx.x;      // 0 .. B*N-1
    int b = gid >> 13, q = gid & (NN - 1);
    float A[KK], Bv[KK];
    const float4* pa = (const float4*)&thrL[(((size_t)b * 2 + 0) * NN + q) * KK];
    const float4* pb = (const float4*)&thrL[(((size_t)b * 2 + 1) * NN + q) * KK];
#pragma unroll
    for (int i = 0; i < 5; ++i) {
        float4 va = pa[i];
        float4 vb = pb[i];
        A[4*i] = va.x;  A[4*i+1] = va.y;  A[4*i+2] = va.z;  A[4*i+3] = va.w;
        Bv[4*i] = vb.x; Bv[4*i+1] = vb.y; Bv[4*i+2] = vb.z; Bv[4*i+3] = vb.w;
    }
    float v = fminf(Bv[KK - 1], A[KK - 1]);        // i=0 and i=20 boundary terms
#pragma unroll
    for (int i = 1; i < KK; ++i)
        v = fminf(v, fmaxf(A[i - 1], Bv[KK - 1 - i]));
    // kT/kS share bitwise-identical d; tiny inflation is pure safety margin
    thr[gid] = v + fabsf(v) * 1e-6f + 1e-6f;
}

// ---------------- kernel S (phase-1): barrier-free register-direct sweep ----------------
// r26: single dispatch restored (r25 split was diagnostic-only, cost ~17 us).
// Proven r22/r5 form: lbuf batched emit, MS=16/CHUNK=512, bounds(256,4), 74.5 us.
__global__ void __launch_bounds__(256, 4)
kS(const _Float16* __restrict__ xh, const _Float16* __restrict__ xl,
   const float* __restrict__ sq, const float* __restrict__ thr,
   int* __restrict__ cnt, u64* __restrict__ cand) {
    __shared__ u64 lbuf[256 * RBS];                // 18 KB (odd stride: conflict-free)
    __shared__ __align__(16) float sqs[CHUNK];     // 2 KB, holds -sq/2
    const int tid  = threadIdx.x;
    const int lane = tid & 63;
    const int wv   = tid >> 6;
    const int qcol = lane & 31;
    const int kh   = lane >> 5;
    const int id     = blockIdx.x;        // 2048 = 16 chunk x 64 qtile x 2 b
    const int ychunk = id & 15;           // chunk c -> XCD c&7 (2 chunks/XCD in L2)
    const int qt     = (id >> 4) & 63;
    const int b      = (id >> 10) & 1;
    const int qbase  = qt * QB + wv * 32;
    const int pbase0 = ychunk * CHUNK;
    const int ptile0 = pbase0 >> 5;

    for (int i = tid; i < CHUNK; i += 256)
        sqs[i] = -0.5f * sq[(size_t)b * NN + pbase0 + i];   // r22: pre-scaled

    f16x8 Qh[4], Ql[4];
    load_qfrag(xh, xl, b, qbase, lane, Qh, Ql);

    const size_t qidx = (size_t)b * NN + qbase + qcol;
    const float tv = thr[qidx];
    const size_t cb = qidx * CAPQ;
    int c_ = 0;

    __syncthreads();   // sqs visible; the ONLY barrier in this kernel

    // one atomic per flush (normally once per lane, at the end)
    auto flushS = [&]() {
        if (c_ > 0) {
            int base = atomicAdd(&cnt[qidx], c_);
#pragma unroll 1
            for (int j = 0; j < c_; ++j) {
                int slot = base + j;
                if (slot < CAPQ) cand[cb + slot] = lbuf[tid * RBS + j];
            }
            c_ = 0;
        }
    };

#pragma unroll 2
    for (int tt = 0; tt < CHUNK / 32; ++tt) {
        f16x8 Ah[4], Al[4];
        load_atile(xh, xl, b, ptile0 + tt, lane, Ah, Al);   // global->reg, L1/L2-hot
        float dv[16];
        dist_from_frags(Ah, Al, sqs, tt * 32, kh, Qh, Ql, dv);

        const int pb4 = pbase0 + tt * 32 + 4 * kh;
#pragma unroll
        for (int i = 0; i < 16; ++i) {
            float d = dv[i];
            if (d <= tv) {                           // rare (~1% of pairs)
                int id2 = pb4 + ((i & 3) + 8 * (i >> 2));
                lbuf[tid * RBS + c_] = ((u64)fmap(d) << 32) | (unsigned)id2;
                if (++c_ == RB) flushS();            // exact, rare overflow guard
            }
        }
    }
    flushS();
}

// ---------------- kernel P (phase-2): exact top-K, 8 lanes per query ----------------
// r26: r7 diagnostic exposed kP = 47.9 us at 4% occupancy (512 waves total, 2/CU;
// serial scan of ~96 scattered loads, nothing to hide latency). Redesign: 8 lanes
// per query (lane s scans slots s, s+8, ...: <=24 each, unroll 4), local top-20 per
// lane (exact: global top-20 elem is in any containing subset's top-20), then
// 3-round shfl merge tree (off=1,2,4; active lanes only insert -> partner list
// untouched within a round, same invariant as the old parity merge).
// 256 thr/block x 512 blocks = 2048 waves = 8 waves/CU (4x occupancy).
__global__ void __launch_bounds__(256, 2)
kP(const int* __restrict__ cnt, const u64* __restrict__ cand,
   int* __restrict__ idxK) {
    const int tid  = threadIdx.x;
    const int lane = tid & 63;
    const int s    = tid & 7;            // slot-lane within query
    const int q    = blockIdx.x * 32 + (tid >> 3);
    int m = cnt[q];
    m = m < CAPQ ? m : CAPQ;
    const int nj = (m - s + 7) >> 3;     // my slot count: s, s+8, ... (<= 24)
    u64 kk[KK];
#pragma unroll
    for (int i = 0; i < KK; ++i) kk[i] = ~0ull;

    auto insU = [&](u64 v) {
        kk[KK - 1] = v;
#pragma unroll
        for (int i = KK - 1; i > 0; --i) {
            u64 a = kk[i - 1], c = kk[i];
            bool sw = c < a;
            kk[i - 1] = sw ? c : a;
            kk[i]     = sw ? a : c;
        }
    };

    // wave-max of nj == iteration bound (same trick as r23, now <= 24)
    int jmax = nj;
#pragma unroll
    for (int off = 32; off > 0; off >>= 1) {
        int o = __shfl_xor(jmax, off);
        jmax = o > jmax ? o : jmax;
    }

    const u64* cp = &cand[(size_t)q * CAPQ + s];
#pragma unroll 4
    for (int j = 0; j < jmax; ++j) {
        u64 v = cp[8 * j];               // in-bounds: s + 8*23 <= 191 < CAPQ
        if ((j < nj) && v < kk[KK - 1]) insU(v);
    }

    // 3-round merge tree within each 8-lane query group (u64 keys: exact order)
#pragma unroll
    for (int r = 0; r < 3; ++r) {
        const int off = 1 << r;
        const bool act = (s & ((off << 1) - 1)) == 0;   // lanes that merge this round
#pragma unroll
        for (int j = 0; j < KK; ++j) {
            u64 v = __shfl(kk[j], lane | off);   // partner sorted ascending, unmodified
            bool ins = act && v < kk[KK - 1];
            if (!__any(ins)) break;
            if (ins) insU(v);
        }
    }

    if (s == 0) {
        int* op = &idxK[(size_t)q * KK];
#pragma unroll
        for (int i = 0; i < KK; ++i) op[i] = (int)(unsigned)(kk[i] & 0xffffffffu);
    }
}

// ---------------- kernel C1: gather + stats + hmax/hmin (o-major out, r17 form) ----------------
__global__ void kC1(const float* __restrict__ y1, const float* __restrict__ y2,
                    const int* __restrict__ idxK, float* __restrict__ hmaxT,
                    float* __restrict__ hminT, float* __restrict__ stats) {
    __shared__ int li[32 * KK];          // all 640 neighbor indices, staged once
    __shared__ float red[256];
    __shared__ float thm[32 * 65];       // [n_local][o], pad 65 -> conflict-free
    __shared__ float thn[32 * 65];
    int b = blockIdx.y;
    int o = threadIdx.x & 63;
    int nn = threadIdx.x >> 6;
    int nbase = blockIdx.x * 32;

    for (int i = threadIdx.x; i < 32 * KK; i += 256)
        li[i] = idxK[((size_t)b * NN + nbase) * KK + i];
    __syncthreads();

    float s = 0.f, ss = 0.f;
    for (int gidx = 0; gidx < 8; ++gidx) {
        int nl = gidx * 4 + nn;
        int n = nbase + nl;
        float y2v = y2[((size_t)b * NN + n) * 64 + o];
        float hm = -FLT_MAX, hn = FLT_MAX;
        const int* lin = &li[nl * KK];
#pragma unroll 4
        for (int k = 0; k < KK; ++k) {
            int j = lin[k];            // wave-uniform (nn fixed per wave)
            float h = y1[((size_t)b * NN + j) * 64 + o] + y2v;   // coalesced 256B, L2-hot
            s += h;
            ss += h * h;
            hm = fmaxf(hm, h);
            hn = fminf(hn, h);
        }
        thm[nl * 65 + o] = hm;
        thn[nl * 65 + o] = hn;
    }
    __syncthreads();

    // transposed store: 8 half-wave groups, each writes 8 o-rows
    int l = threadIdx.x & 31, g = threadIdx.x >> 5;
#pragma unroll
    for (int i = 0; i < 8; ++i) {
        int o2 = g * 8 + i;
        hmaxT[((size_t)b * 64 + o2) * NN + nbase + l] = thm[l * 65 + o2];
        hminT[((size_t)b * 64 + o2) * NN + nbase + l] = thn[l * 65 + o2];
    }

    __syncthreads();
    red[threadIdx.x] = s;
    __syncthreads();
    if (threadIdx.x < 64) {
        float v = red[o] + red[64 + o] + red[128 + o] + red[192 + o];
        atomicAdd(&stats[o], v);
    }
    __syncthreads();
    red[threadIdx.x] = ss;
    __syncthreads();
    if (threadIdx.x < 64) {
        float v = red[o] + red[64 + o] + red[128 + o] + red[192 + o];
        atomicAdd(&stats[64 + o], v);
    }
}

// ---------------- kernel C3: finalize BN + leaky + max-over-k (all coalesced) ----------------
__global__ void kC3(const float* __restrict__ hmaxT, const float* __restrict__ hminT,
                    const float* __restrict__ stats, const float* __restrict__ gamma,
                    const float* __restrict__ beta, float* __restrict__ out) {
    int o = blockIdx.x;
    int half = blockIdx.y;
    int b = blockIdx.z;
    const float c = (float)BB * NN * KK;
    float mean = stats[o] / c;
    float var = stats[64 + o] / c - mean * mean;
    float rs = rsqrtf(var + 1e-5f);
    float a = gamma[o] * rs;
    float b2 = beta[o] - a * mean;
    size_t rowb = ((size_t)b * 64 + o) * NN;
    int n0 = half * (NN / 2), n1 = n0 + NN / 2;
    for (int n = n0 + threadIdx.x; n < n1; n += 256) {
        float hm = hmaxT[rowb + n];    // coalesced
        float hn = hminT[rowb + n];
        float hs = (a >= 0.f) ? hm : hn;   // affine monotone: max or min per sign of a
        float v = a * hs + b2;
        v = (v >= 0.f) ? v : 0.2f * v;
        out[rowb + n] = v;             // coalesced
    }
}

extern "C" void kernel_launch(void* const* d_in, const int* in_sizes, int n_in,
                              void* d_out, int out_size, void* d_ws, size_t ws_size,
                              hipStream_t stream) {
    const float* x     = (const float*)d_in[0];
    const float* W     = (const float*)d_in[1];
    const float* gamma = (const float*)d_in[2];
    const float* beta  = (const float*)d_in[3];
    float* out = (float*)d_out;
    float* ws  = (float*)d_ws;

    _Float16* xh = (_Float16*)(ws + XH_OFF);
    _Float16* xl = (_Float16*)(ws + XL_OFF);
    float* sq    = ws + SQ_OFF;
    float* y1    = ws + Y1_OFF;
    float* y2    = ws + Y2_OFF;
    float* thr   = ws + TH_OFF;
    int*   cnt   = (int*)(ws + CN_OFF);
    float* thrL  = ws + TL_OFF;
    u64*   cand  = (u64*)(ws + CA_OFF);
    int*   idxK  = (int*)(ws + IX_OFF);
    float* hmaxT = ws + HX_OFF;
    float* hminT = ws + HN_OFF;
    float* stats = ws + ST_OFF;

    kA<<<dim3(NN / 64, 2, BB), 256, 0, stream>>>(x, W, ws);
    kT<<<dim3(NN / 32, 2 * BB), 256, 0, stream>>>(xh, xl, sq, thrL);
    kM2<<<dim3(BB * NN / 256), 256, 0, stream>>>(thrL, thr);
    kS<<<dim3(MS * (NN / QB) * BB), 256, 0, stream>>>(xh, xl, sq, thr, cnt, cand);
    kP<<<dim3(BB * NN / 32), 256, 0, stream>>>(cnt, cand, idxK);
    kC1<<<dim3(NN / 32, BB), 256, 0, stream>>>(y1, y2, idxK, hmaxT, hminT, stats);
    kC3<<<dim3(OO, 2, BB), 256, 0, stream>>>(hmaxT, hminT, stats, gamma, beta, out);
}

// Round 10
// 267.462 us; speedup vs baseline: 1.1338x; 1.1338x over previous
//
#include <hip/hip_runtime.h>
#include <cfloat>

#define BB 2
#define NN 8192
#define OO 64
#define KK 20
#define QB 128        // queries per kS block (4 waves x 32)
#define MS 16         // point splits in kS (2048 blocks -> 8 blocks/CU by resources)
#define CHUNK 512     // points per kS split (128 KB, L2-pinned, 2 chunks/XCD)
#define CAPQ 192      // candidate slots per query (tight thr: mean ~80)
#define RB 8          // kS per-lane buffer depth
#define RBS 9         // lbuf stride in u64; ODD stride -> conflict-free

using f16x8  = __attribute__((ext_vector_type(8))) _Float16;
using f32x16 = __attribute__((ext_vector_type(16))) float;
typedef unsigned long long u64;

// ws layout (float units)
#define XH_OFF ((size_t)0)
#define XL_OFF (XH_OFF + (size_t)BB*NN*32)
#define SQ_OFF (XL_OFF + (size_t)BB*NN*32)        // B*N
#define Y1_OFF (SQ_OFF + (size_t)BB*NN)           // B*N*64 (n-major rows)
#define Y2_OFF (Y1_OFF + (size_t)BB*NN*64)        // B*N*64 (n-major rows)
#define TH_OFF (Y2_OFF + (size_t)BB*NN*64)        // B*N thresholds (float)
#define CN_OFF (TH_OFF + (size_t)BB*NN)           // B*N counters (int)
#define TL_OFF (CN_OFF + (size_t)BB*NN)           // 2*B*N*KK half-sample top-20 lists
#define CA_OFF (TL_OFF + (size_t)2*BB*NN*KK)      // B*N*CAPQ u64
#define IX_OFF (CA_OFF + (size_t)BB*NN*CAPQ*2)    // B*N*K (int)
#define HX_OFF (IX_OFF + (size_t)BB*NN*KK)        // B*64*N (o-major)
#define HN_OFF (HX_OFF + (size_t)BB*NN*64)        // B*64*N (o-major)
#define ST_OFF (HN_OFF + (size_t)BB*NN*64)        // 128

// MFMA-native swizzled fragment layout (verified r6-18)
__device__ __forceinline__ size_t frag_off(int b, int tile, int t, int lane) {
    return ((((size_t)b * (NN / 32) + tile) * 4 + t) * 64 + lane) * 8;
}

// order-preserving float->uint map (works for negatives too)
__device__ __forceinline__ unsigned fmap(float f) {
    unsigned u = __float_as_uint(f);
    return (u & 0x80000000u) ? ~u : (u | 0x80000000u);
}

// ---------- branchless selection primitives ----------
__device__ __forceinline__ void sort16(float* v) {      // bitonic, ascending
#pragma unroll
    for (int k = 2; k <= 16; k <<= 1) {
#pragma unroll
        for (int j = k >> 1; j > 0; j >>= 1) {
#pragma unroll
            for (int i = 0; i < 16; ++i) {
                int l = i ^ j;
                if (l > i) {
                    bool up = ((i & k) == 0);
                    float mn = fminf(v[i], v[l]);
                    float mx = fmaxf(v[i], v[l]);
                    v[i] = up ? mn : mx;
                    v[l] = up ? mx : mn;
                }
            }
        }
    }
}
__device__ __forceinline__ void bmerge32(float* A) {    // bitonic input -> ascending
#pragma unroll
    for (int j = 16; j > 0; j >>= 1) {
#pragma unroll
        for (int i = 0; i < 32; ++i) {
            if ((i & j) == 0) {
                float mn = fminf(A[i], A[i | j]);
                float mx = fmaxf(A[i], A[i | j]);
                A[i] = mn;
                A[i | j] = mx;
            }
        }
    }
}
// A(32, asc) <- 32 smallest of A U B(16, asc)
__device__ __forceinline__ void merge32_16(float* A, const float* B) {
#pragma unroll
    for (int i = 16; i < 32; ++i) A[i] = fminf(A[i], B[31 - i]);
    bmerge32(A);
}
// A(32, asc) <- 32 smallest of A U B(32, asc)
__device__ __forceinline__ void merge32_32(float* A, const float* B) {
    float t[32];
#pragma unroll
    for (int i = 0; i < 32; ++i) t[i] = fminf(A[i], B[31 - i]);
    bmerge32(t);
#pragma unroll
    for (int i = 0; i < 32; ++i) A[i] = t[i];
}

// ---------- distance tile pieces: 32 points x 32 queries, hi/lo fp16 MFMA ----------
// C: col=lane&31 (query), row = (i&3) + 8*(i>>2) + 4*kh.  Verified rounds 3-18.
__device__ __forceinline__ void load_atile(const _Float16* __restrict__ xh,
                                           const _Float16* __restrict__ xl,
                                           int b, int ptile, int lane,
                                           f16x8* Ah, f16x8* Al) {
#pragma unroll
    for (int t = 0; t < 4; ++t) {
        size_t o = frag_off(b, ptile, t, lane);
        Ah[t] = *(const f16x8*)&xh[o];   // coalesced: 64 lanes x 16 B contiguous
        Al[t] = *(const f16x8*)&xl[o];
    }
}

// r22: sqs holds -sq/2 (pre-scaled at staging). c0 is INITIALIZED from sqs, so the
// MFMA chain computes -sq/2 + dot_hi directly. Shared by kT and kS -> d stays
// bitwise-identical across both kernels (the kM2 threshold invariant).
__device__ __forceinline__ void dist_from_frags(const f16x8* Ah, const f16x8* Al,
                                                const float* sqs, int sbase, int kh,
                                                const f16x8* Qh, const f16x8* Ql,
                                                float* dv) {
    f32x16 c0, c1;
#pragma unroll
    for (int r2 = 0; r2 < 4; ++r2) {
        float4 sv = *(const float4*)&sqs[sbase + 8 * r2 + 4 * kh];  // -sq/2, LDS broadcast
        c0[4 * r2 + 0] = sv.x;
        c0[4 * r2 + 1] = sv.y;
        c0[4 * r2 + 2] = sv.z;
        c0[4 * r2 + 3] = sv.w;
    }
#pragma unroll
    for (int i = 0; i < 16; ++i) c1[i] = 0.f;
#pragma unroll
    for (int t = 0; t < 4; ++t) {
        c0 = __builtin_amdgcn_mfma_f32_32x32x16_f16(Ah[t], Qh[t], c0, 0, 0, 0); // -sq/2 + hi*hi
        c1 = __builtin_amdgcn_mfma_f32_32x32x16_f16(Ah[t], Ql[t], c1, 0, 0, 0); // hi*lo
        c1 = __builtin_amdgcn_mfma_f32_32x32x16_f16(Al[t], Qh[t], c1, 0, 0, 0); // lo*hi
    }
#pragma unroll
    for (int i = 0; i < 16; ++i)
        dv[i] = fmaf(-2.f, c0[i], -9.765625e-4f * c1[i]);  // d = sq - 2dot - cross
}

__device__ __forceinline__ void load_qfrag(const _Float16* __restrict__ xh,
                                           const _Float16* __restrict__ xl,
                                           int b, int qbase, int lane,
                                           f16x8* Qh, f16x8* Ql) {
    const int qtile = qbase >> 5;
#pragma unroll
    for (int t = 0; t < 4; ++t) {
        size_t o = frag_off(b, qtile, t, lane);
        Qh[t] = *(const f16x8*)&xh[o];
        Ql[t] = *(const f16x8*)&xl[o];
    }
}

// ---------------- kernel A: sq + fp16 hi/lo split (swizzled) + y1/y2 ----------------
// r17 structure: x staged in LDS once; o-split into 2 groups of 32.
__global__ void __launch_bounds__(256, 2)
kA(const float* __restrict__ x, const float* __restrict__ W,
   float* __restrict__ ws) {
    __shared__ __align__(16) float w1s[32 * 64];   // 8 KB: this block's 32 o rows
    __shared__ __align__(16) float w2s[32 * 64];   // 8 KB
    __shared__ float xs[64 * 65];                  // 16.6 KB [c][n], pad 65
    __shared__ float tb[64 * 33];                  // 8.4 KB transpose, pad 33
    const int bb = blockIdx.z;
    const int og = blockIdx.y;        // o-group: 0 or 1
    const int obase = og * 32;
    const int nbase = blockIdx.x * 64;
    const int tn = threadIdx.x & 63, tq = threadIdx.x >> 6;

    // W slice (32 o x 64 c), w2 = W_right - W_left
    for (int i = threadIdx.x; i < 2048; i += 256) {
        int ol = i >> 6, c = i & 63;
        float a = W[(obase + ol) * 128 + c];
        float d = W[(obase + ol) * 128 + 64 + c];
        w1s[i] = a;
        w2s[i] = d - a;
    }
    // x tile: [c][n] staged coalesced (256 B per row-segment)
    for (int i = threadIdx.x; i < 4096; i += 256) {
        int c = i >> 6, nl = i & 63;
        xs[c * 65 + nl] = x[((size_t)bb * 64 + c) * NN + nbase + nl];
    }
    if (og == 0) {
        if (blockIdx.x == 0 && bb == 0 && threadIdx.x < 128)
            ws[ST_OFF + threadIdx.x] = 0.f;   // zero stats accumulators (pre-kC1)
        int gid = (bb * 128 + blockIdx.x) * 256 + threadIdx.x;  // init cnt (pre-kS)
        if (gid < BB * NN) ((int*)(ws + CN_OFF))[gid] = 0;
    }
    __syncthreads();

    // per-thread column n = tn (conflict-free: bank = (c+tn)%32)
    float xc[64];
#pragma unroll
    for (int c = 0; c < 64; ++c) xc[c] = xs[c * 65 + tn];

    if (og == 0 && tq == 0) {   // sq + swizzled fp16 split (one wave, per-n)
        float sqv = 0.f;
#pragma unroll
        for (int c = 0; c < 64; ++c) sqv = fmaf(xc[c], xc[c], sqv);
        int n = nbase + tn;
        ws[SQ_OFF + (size_t)bb * NN + n] = sqv;
        _Float16* xh = (_Float16*)(ws + XH_OFF);
        _Float16* xl = (_Float16*)(ws + XL_OFF);
        int tile = n >> 5, r = n & 31;
#pragma unroll
        for (int t = 0; t < 4; ++t) {
#pragma unroll
            for (int kh = 0; kh < 2; ++kh) {
                f16x8 vh, vl;
#pragma unroll
                for (int j = 0; j < 8; ++j) {
                    float v = xc[t * 16 + kh * 8 + j];
                    _Float16 h = (_Float16)v;
                    vh[j] = h;
                    vl[j] = (_Float16)((v - (float)h) * 2048.f);  // x = hi + lo*2^-11
                }
                size_t o = frag_off(bb, tile, t, kh * 32 + r);    // lane-consecutive
                *(f16x8*)&xh[o] = vh;
                *(f16x8*)&xl[o] = vl;
            }
        }
    }

    // projections: thread = n, 8 o's each (o_local = tq*8 + o2)
    float a1v[8], a2v[8];
#pragma unroll
    for (int o2 = 0; o2 < 8; ++o2) {
        int ol = tq * 8 + o2;
        const float4* w1v = (const float4*)&w1s[ol * 64];
        const float4* w2v = (const float4*)&w2s[ol * 64];
        float a1 = 0.f, a2 = 0.f;
#pragma unroll
        for (int c4 = 0; c4 < 16; ++c4) {
            float4 v1 = w1v[c4];   // broadcast ds_read_b128
            float4 v2 = w2v[c4];
            a1 = fmaf(v1.x, xc[4*c4],   a1);
            a1 = fmaf(v1.y, xc[4*c4+1], a1);
            a1 = fmaf(v1.z, xc[4*c4+2], a1);
            a1 = fmaf(v1.w, xc[4*c4+3], a1);
            a2 = fmaf(v2.x, xc[4*c4],   a2);
            a2 = fmaf(v2.y, xc[4*c4+1], a2);
            a2 = fmaf(v2.z, xc[4*c4+2], a2);
            a2 = fmaf(v2.w, xc[4*c4+3], a2);
        }
        a1v[o2] = a1;
        a2v[o2] = a2;
    }

    // y1: transpose through tb, then full-line stores (2 rows x 128 B per instr)
    const int lo = threadIdx.x & 31;          // o_local
    const int lp = (threadIdx.x >> 5) & 1;    // row parity
#pragma unroll
    for (int o2 = 0; o2 < 8; ++o2)
        tb[tn * 33 + tq * 8 + o2] = a1v[o2];
    __syncthreads();
#pragma unroll
    for (int j = 0; j < 8; ++j) {
        int r = tq * 16 + 2 * j + lp;
        ws[Y1_OFF + ((size_t)bb * NN + nbase + r) * 64 + obase + lo] = tb[r * 33 + lo];
    }
    __syncthreads();
#pragma unroll
    for (int o2 = 0; o2 < 8; ++o2)
        tb[tn * 33 + tq * 8 + o2] = a2v[o2];
    __syncthreads();
#pragma unroll
    for (int j = 0; j < 8; ++j) {
        int r = tq * 16 + 2 * j + lp;
        ws[Y2_OFF + ((size_t)bb * NN + nbase + r) * 64 + obase + lo] = tb[r * 33 + lo];
    }
}

// ---------------- kernel T (phase-0): half-sample top-20 lists, branchless networks ----------------
__global__ void __launch_bounds__(256, 3)
kT(const _Float16* __restrict__ xh, const _Float16* __restrict__ xl,
   const float* __restrict__ sq, float* __restrict__ thrL) {
    __shared__ float mrg[32 * 128];          // [j][wave*32+qc]
    __shared__ __align__(16) float sqs[1024];  // staged -sq/2 slice (lgkmcnt path)
    const int tid  = threadIdx.x;
    const int lane = tid & 63;
    const int wv   = tid >> 6;
    const int qcol = lane & 31;
    const int kh   = lane >> 5;
    const int b     = blockIdx.y >> 1;
    const int s     = blockIdx.y & 1;     // sample half
    const int qbase = blockIdx.x * 32;

    for (int i = tid; i < 1024; i += 256)
        sqs[i] = -0.5f * sq[(size_t)b * NN + s * 1024 + i];   // r22: pre-scaled

    f16x8 Qh[4], Ql[4];
    load_qfrag(xh, xl, b, qbase, lane, Qh, Ql);
    __syncthreads();

    float dk[32];
#pragma unroll
    for (int i = 0; i < 32; ++i) dk[i] = FLT_MAX;

    const int p0 = s * 1024 + wv * 256;
    for (int pt = p0; pt < p0 + 256; pt += 32) {
        f16x8 Ah[4], Al[4];
        load_atile(xh, xl, b, pt >> 5, lane, Ah, Al);
        float dv[16];
        dist_from_frags(Ah, Al, sqs, pt - s * 1024, kh, Qh, Ql, dv);
        float m16 = dv[0];
#pragma unroll
        for (int i = 1; i < 16; ++i) m16 = fminf(m16, dv[i]);
        if (__any(m16 < dk[KK - 1])) {   // wave-uniform tile skip (late tiles)
            sort16(dv);
            merge32_16(dk, dv);
        }
    }

    // kh pair merge via shfl (branchless; kh==1 lanes self-merge harmlessly)
    {
        float B[32];
#pragma unroll
        for (int j = 0; j < 32; ++j) B[j] = __shfl(dk[j], lane | 32);
        merge32_32(dk, B);
    }
    if (kh == 0) {
#pragma unroll
        for (int j = 0; j < 32; ++j) mrg[j * 128 + wv * 32 + qcol] = dk[j];
    }
    __syncthreads();

    // cross-wave merge: wave 0, lanes 0-31, one query per lane; emit sorted 20-list
    if (tid < 32) {
        float B[32];
#pragma unroll 1
        for (int w = 1; w < 4; ++w) {
#pragma unroll
            for (int j = 0; j < 32; ++j) B[j] = mrg[j * 128 + w * 32 + tid];
            merge32_32(dk, B);
        }
        size_t base = (((size_t)b * 2 + s) * NN + qbase + tid) * KK;
#pragma unroll
        for (int j = 0; j < KK; ++j) thrL[base + j] = dk[j];
    }
}

// ---------------- kernel M2: exact union 20th via k-th-of-two-sorted identity ----------------
// r18-keep: ans = min_{i} max(A[i-1], B[19-i]) -- 10 independent float4 loads.
__global__ void kM2(const float* __restrict__ thrL, float* __restrict__ thr) {
    int gid = blockIdx.x * 256 + threadIdx.x;      // 0 .. B*N-1
    int b = gid >> 13, q = gid & (NN - 1);
    float A[KK], Bv[KK];
    const float4* pa = (const float4*)&thrL[(((size_t)b * 2 + 0) * NN + q) * KK];
    const float4* pb = (const float4*)&thrL[(((size_t)b * 2 + 1) * NN + q) * KK];
#pragma unroll
    for (int i = 0; i < 5; ++i) {
        float4 va = pa[i];
        float4 vb = pb[i];
        A[4*i] = va.x;  A[4*i+1] = va.y;  A[4*i+2] = va.z;  A[4*i+3] = va.w;
        Bv[4*i] = vb.x; Bv[4*i+1] = vb.y; Bv[4*i+2] = vb.z; Bv[4*i+3] = vb.w;
    }
    float v = fminf(Bv[KK - 1], A[KK - 1]);        // i=0 and i=20 boundary terms
#pragma unroll
    for (int i = 1; i < KK; ++i)
        v = fminf(v, fmaxf(A[i - 1], Bv[KK - 1 - i]));
    // kT/kS share bitwise-identical d; tiny inflation is pure safety margin
    thr[gid] = v + fabsf(v) * 1e-6f + 1e-6f;
}

// ---------------- kernel S (phase-1): barrier-free register-direct sweep ----------------
// Proven r22/r5 form: lbuf batched emit, MS=16/CHUNK=512, bounds(256,4), 74.5 us.
__global__ void __launch_bounds__(256, 4)
kS(const _Float16* __restrict__ xh, const _Float16* __restrict__ xl,
   const float* __restrict__ sq, const float* __restrict__ thr,
   int* __restrict__ cnt, u64* __restrict__ cand) {
    __shared__ u64 lbuf[256 * RBS];                // 18 KB (odd stride: conflict-free)
    __shared__ __align__(16) float sqs[CHUNK];     // 2 KB, holds -sq/2
    const int tid  = threadIdx.x;
    const int lane = tid & 63;
    const int wv   = tid >> 6;
    const int qcol = lane & 31;
    const int kh   = lane >> 5;
    const int id     = blockIdx.x;        // 2048 = 16 chunk x 64 qtile x 2 b
    const int ychunk = id & 15;           // chunk c -> XCD c&7 (2 chunks/XCD in L2)
    const int qt     = (id >> 4) & 63;
    const int b      = (id >> 10) & 1;
    const int qbase  = qt * QB + wv * 32;
    const int pbase0 = ychunk * CHUNK;
    const int ptile0 = pbase0 >> 5;

    for (int i = tid; i < CHUNK; i += 256)
        sqs[i] = -0.5f * sq[(size_t)b * NN + pbase0 + i];   // r22: pre-scaled

    f16x8 Qh[4], Ql[4];
    load_qfrag(xh, xl, b, qbase, lane, Qh, Ql);

    const size_t qidx = (size_t)b * NN + qbase + qcol;
    const float tv = thr[qidx];
    const size_t cb = qidx * CAPQ;
    int c_ = 0;

    __syncthreads();   // sqs visible; the ONLY barrier in this kernel

    // one atomic per flush (normally once per lane, at the end)
    auto flushS = [&]() {
        if (c_ > 0) {
            int base = atomicAdd(&cnt[qidx], c_);
#pragma unroll 1
            for (int j = 0; j < c_; ++j) {
                int slot = base + j;
                if (slot < CAPQ) cand[cb + slot] = lbuf[tid * RBS + j];
            }
            c_ = 0;
        }
    };

#pragma unroll 2
    for (int tt = 0; tt < CHUNK / 32; ++tt) {
        f16x8 Ah[4], Al[4];
        load_atile(xh, xl, b, ptile0 + tt, lane, Ah, Al);   // global->reg, L1/L2-hot
        float dv[16];
        dist_from_frags(Ah, Al, sqs, tt * 32, kh, Qh, Ql, dv);

        const int pb4 = pbase0 + tt * 32 + 4 * kh;
#pragma unroll
        for (int i = 0; i < 16; ++i) {
            float d = dv[i];
            if (d <= tv) {                           // rare (~1% of pairs)
                int id2 = pb4 + ((i & 3) + 8 * (i >> 2));
                lbuf[tid * RBS + c_] = ((u64)fmap(d) << 32) | (unsigned)id2;
                if (++c_ == RB) flushS();            // exact, rare overflow guard
            }
        }
    }
    flushS();
}

// ---------------- kernel P (phase-2): exact top-K, 8 lanes per query ----------------
// r27: r8's regression diagnosed via VGPR_Count=28 -- kk[20] (40 VGPRs min) was in
// SCRATCH, because the merge loops' data-dependent `break` prevented full unroll ->
// runtime-indexed kk -> array demoted to local memory (skill rule #20). Fix: NO
// breaks anywhere; all loops over kk are compile-time trip count, fully unrolled,
// every index static -> register-resident. The break was only an early-out; running
// all 20 predicated iterations is semantically identical.
__global__ void __launch_bounds__(256, 2)
kP(const int* __restrict__ cnt, const u64* __restrict__ cand,
   int* __restrict__ idxK) {
    const int tid  = threadIdx.x;
    const int lane = tid & 63;
    const int s    = tid & 7;            // slot-lane within query
    const int q    = blockIdx.x * 32 + (tid >> 3);
    int m = cnt[q];
    m = m < CAPQ ? m : CAPQ;
    const int nj = (m - s + 7) >> 3;     // my slot count: s, s+8, ... (<= 24)
    u64 kk[KK];
#pragma unroll
    for (int i = 0; i < KK; ++i) kk[i] = ~0ull;

    auto insU = [&](u64 v) {             // fully static 20-deep compare-swap chain
        kk[KK - 1] = v;
#pragma unroll
        for (int i = KK - 1; i > 0; --i) {
            u64 a = kk[i - 1], c = kk[i];
            bool sw = c < a;
            kk[i - 1] = sw ? c : a;
            kk[i]     = sw ? a : c;
        }
    };

    // wave-max of nj == iteration bound (<= 24)
    int jmax = nj;
#pragma unroll
    for (int off = 32; off > 0; off >>= 1) {
        int o = __shfl_xor(jmax, off);
        jmax = o > jmax ? o : jmax;
    }

    const u64* cp = &cand[(size_t)q * CAPQ + s];
#pragma unroll 4
    for (int j = 0; j < jmax; ++j) {
        u64 v = cp[8 * j];               // in-bounds: s + 8*23 <= 191 < CAPQ
        if ((j < nj) && v < kk[KK - 1]) insU(v);
    }

    // 3-round merge tree within each 8-lane query group (u64 keys: exact order).
    // NO break: constant trip count keeps kk register-resident. Inactive lanes
    // never insert, so each active lane reads its partner's unmodified list.
#pragma unroll
    for (int r = 0; r < 3; ++r) {
        const int off = 1 << r;
        const bool act = (s & ((off << 1) - 1)) == 0;   // lanes that merge this round
#pragma unroll
        for (int j = 0; j < KK; ++j) {
            u64 v = __shfl(kk[j], lane | off);   // partner sorted asc, unmodified
            if (act && v < kk[KK - 1]) insU(v);
        }
    }

    if (s == 0) {
        int* op = &idxK[(size_t)q * KK];
#pragma unroll
        for (int i = 0; i < KK; ++i) op[i] = (int)(unsigned)(kk[i] & 0xffffffffu);
    }
}

// ---------------- kernel C1: gather + stats + hmax/hmin (o-major out, r17 form) ----------------
__global__ void kC1(const float* __restrict__ y1, const float* __restrict__ y2,
                    const int* __restrict__ idxK, float* __restrict__ hmaxT,
                    float* __restrict__ hminT, float* __restrict__ stats) {
    __shared__ int li[32 * KK];          // all 640 neighbor indices, staged once
    __shared__ float red[256];
    __shared__ float thm[32 * 65];       // [n_local][o], pad 65 -> conflict-free
    __shared__ float thn[32 * 65];
    int b = blockIdx.y;
    int o = threadIdx.x & 63;
    int nn = threadIdx.x >> 6;
    int nbase = blockIdx.x * 32;

    for (int i = threadIdx.x; i < 32 * KK; i += 256)
        li[i] = idxK[((size_t)b * NN + nbase) * KK + i];
    __syncthreads();

    float s = 0.f, ss = 0.f;
    for (int gidx = 0; gidx < 8; ++gidx) {
        int nl = gidx * 4 + nn;
        int n = nbase + nl;
        float y2v = y2[((size_t)b * NN + n) * 64 + o];
        float hm = -FLT_MAX, hn = FLT_MAX;
        const int* lin = &li[nl * KK];
#pragma unroll 4
        for (int k = 0; k < KK; ++k) {
            int j = lin[k];            // wave-uniform (nn fixed per wave)
            float h = y1[((size_t)b * NN + j) * 64 + o] + y2v;   // coalesced 256B, L2-hot
            s += h;
            ss += h * h;
            hm = fmaxf(hm, h);
            hn = fminf(hn, h);
        }
        thm[nl * 65 + o] = hm;
        thn[nl * 65 + o] = hn;
    }
    __syncthreads();

    // transposed store: 8 half-wave groups, each writes 8 o-rows
    int l = threadIdx.x & 31, g = threadIdx.x >> 5;
#pragma unroll
    for (int i = 0; i < 8; ++i) {
        int o2 = g * 8 + i;
        hmaxT[((size_t)b * 64 + o2) * NN + nbase + l] = thm[l * 65 + o2];
        hminT[((size_t)b * 64 + o2) * NN + nbase + l] = thn[l * 65 + o2];
    }

    __syncthreads();
    red[threadIdx.x] = s;
    __syncthreads();
    if (threadIdx.x < 64) {
        float v = red[o] + red[64 + o] + red[128 + o] + red[192 + o];
        atomicAdd(&stats[o], v);
    }
    __syncthreads();
    red[threadIdx.x] = ss;
    __syncthreads();
    if (threadIdx.x < 64) {
        float v = red[o] + red[64 + o] + red[128 + o] + red[192 + o];
        atomicAdd(&stats[64 + o], v);
    }
}

// ---------------- kernel C3: finalize BN + leaky + max-over-k (all coalesced) ----------------
__global__ void kC3(const float* __restrict__ hmaxT, const float* __restrict__ hminT,
                    const float* __restrict__ stats, const float* __restrict__ gamma,
                    const float* __restrict__ beta, float* __restrict__ out) {
    int o = blockIdx.x;
    int half = blockIdx.y;
    int b = blockIdx.z;
    const float c = (float)BB * NN * KK;
    float mean = stats[o] / c;
    float var = stats[64 + o] / c - mean * mean;
    float rs = rsqrtf(var + 1e-5f);
    float a = gamma[o] * rs;
    float b2 = beta[o] - a * mean;
    size_t rowb = ((size_t)b * 64 + o) * NN;
    int n0 = half * (NN / 2), n1 = n0 + NN / 2;
    for (int n = n0 + threadIdx.x; n < n1; n += 256) {
        float hm = hmaxT[rowb + n];    // coalesced
        float hn = hminT[rowb + n];
        float hs = (a >= 0.f) ? hm : hn;   // affine monotone: max or min per sign of a
        float v = a * hs + b2;
        v = (v >= 0.f) ? v : 0.2f * v;
        out[rowb + n] = v;             // coalesced
    }
}

extern "C" void kernel_launch(void* const* d_in, const int* in_sizes, int n_in,
                              void* d_out, int out_size, void* d_ws, size_t ws_size,
                              hipStream_t stream) {
    const float* x     = (const float*)d_in[0];
    const float* W     = (const float*)d_in[1];
    const float* gamma = (const float*)d_in[2];
    const float* beta  = (const float*)d_in[3];
    float* out = (float*)d_out;
    float* ws  = (float*)d_ws;

    _Float16* xh = (_Float16*)(ws + XH_OFF);
    _Float16* xl = (_Float16*)(ws + XL_OFF);
    float* sq    = ws + SQ_OFF;
    float* y1    = ws + Y1_OFF;
    float* y2    = ws + Y2_OFF;
    float* thr   = ws + TH_OFF;
    int*   cnt   = (int*)(ws + CN_OFF);
    float* thrL  = ws + TL_OFF;
    u64*   cand  = (u64*)(ws + CA_OFF);
    int*   idxK  = (int*)(ws + IX_OFF);
    float* hmaxT = ws + HX_OFF;
    float* hminT = ws + HN_OFF;
    float* stats = ws + ST_OFF;

    kA<<<dim3(NN / 64, 2, BB), 256, 0, stream>>>(x, W, ws);
    kT<<<dim3(NN / 32, 2 * BB), 256, 0, stream>>>(xh, xl, sq, thrL);
    kM2<<<dim3(BB * NN / 256), 256, 0, stream>>>(thrL, thr);
    kS<<<dim3(MS * (NN / QB) * BB), 256, 0, stream>>>(xh, xl, sq, thr, cnt, cand);
    kP<<<dim3(BB * NN / 32), 256, 0, stream>>>(cnt, cand, idxK);
    kC1<<<dim3(NN / 32, BB), 256, 0, stream>>>(y1, y2, idxK, hmaxT, hminT, stats);
    kC3<<<dim3(OO, 2, BB), 256, 0, stream>>>(hmaxT, hminT, stats, gamma, beta, out);
}

// Round 11
// 247.414 us; speedup vs baseline: 1.2257x; 1.0810x over previous
//
#include <hip/hip_runtime.h>
#include <cfloat>

#define BB 2
#define NN 8192
#define OO 64
#define KK 20
#define QB 128        // queries per kS block (4 waves x 32)
#define MS 16         // point splits in kS (2048 blocks -> 8 blocks/CU by resources)
#define CHUNK 512     // points per kS split (128 KB, L2-pinned, 2 chunks/XCD)
#define CAPQ 192      // candidate slots per query (tight thr: mean ~80)
#define RB 8          // kS per-lane buffer depth
#define RBS 9         // lbuf stride in u64; ODD stride -> conflict-free

using f16x8  = __attribute__((ext_vector_type(8))) _Float16;
using f32x16 = __attribute__((ext_vector_type(16))) float;
typedef unsigned long long u64;

// ws layout (float units)
#define XH_OFF ((size_t)0)
#define XL_OFF (XH_OFF + (size_t)BB*NN*32)
#define SQ_OFF (XL_OFF + (size_t)BB*NN*32)        // B*N
#define Y1_OFF (SQ_OFF + (size_t)BB*NN)           // B*N*64 (n-major rows)
#define Y2_OFF (Y1_OFF + (size_t)BB*NN*64)        // B*N*64 (n-major rows)
#define TH_OFF (Y2_OFF + (size_t)BB*NN*64)        // B*N thresholds (float)
#define CN_OFF (TH_OFF + (size_t)BB*NN)           // B*N counters (int)
#define TL_OFF (CN_OFF + (size_t)BB*NN)           // 2*B*N*KK half-sample top-20 lists
#define CA_OFF (TL_OFF + (size_t)2*BB*NN*KK)      // B*N*CAPQ u64
#define IX_OFF (CA_OFF + (size_t)BB*NN*CAPQ*2)    // B*N*K (int)
#define HX_OFF (IX_OFF + (size_t)BB*NN*KK)        // B*64*N (o-major)
#define HN_OFF (HX_OFF + (size_t)BB*NN*64)        // B*64*N (o-major)
#define ST_OFF (HN_OFF + (size_t)BB*NN*64)        // 128

// MFMA-native swizzled fragment layout (verified r6-18)
__device__ __forceinline__ size_t frag_off(int b, int tile, int t, int lane) {
    return ((((size_t)b * (NN / 32) + tile) * 4 + t) * 64 + lane) * 8;
}

// order-preserving float->uint map (works for negatives too)
__device__ __forceinline__ unsigned fmap(float f) {
    unsigned u = __float_as_uint(f);
    return (u & 0x80000000u) ? ~u : (u | 0x80000000u);
}

// ---------- branchless selection primitives ----------
__device__ __forceinline__ void sort16(float* v) {      // bitonic, ascending
#pragma unroll
    for (int k = 2; k <= 16; k <<= 1) {
#pragma unroll
        for (int j = k >> 1; j > 0; j >>= 1) {
#pragma unroll
            for (int i = 0; i < 16; ++i) {
                int l = i ^ j;
                if (l > i) {
                    bool up = ((i & k) == 0);
                    float mn = fminf(v[i], v[l]);
                    float mx = fmaxf(v[i], v[l]);
                    v[i] = up ? mn : mx;
                    v[l] = up ? mx : mn;
                }
            }
        }
    }
}
__device__ __forceinline__ void bmerge32(float* A) {    // bitonic input -> ascending
#pragma unroll
    for (int j = 16; j > 0; j >>= 1) {
#pragma unroll
        for (int i = 0; i < 32; ++i) {
            if ((i & j) == 0) {
                float mn = fminf(A[i], A[i | j]);
                float mx = fmaxf(A[i], A[i | j]);
                A[i] = mn;
                A[i | j] = mx;
            }
        }
    }
}
// A(32, asc) <- 32 smallest of A U B(16, asc)
__device__ __forceinline__ void merge32_16(float* A, const float* B) {
#pragma unroll
    for (int i = 16; i < 32; ++i) A[i] = fminf(A[i], B[31 - i]);
    bmerge32(A);
}
// A(32, asc) <- 32 smallest of A U B(32, asc)
__device__ __forceinline__ void merge32_32(float* A, const float* B) {
    float t[32];
#pragma unroll
    for (int i = 0; i < 32; ++i) t[i] = fminf(A[i], B[31 - i]);
    bmerge32(t);
#pragma unroll
    for (int i = 0; i < 32; ++i) A[i] = t[i];
}

// ---------- distance tile pieces: 32 points x 32 queries, hi/lo fp16 MFMA ----------
// C: col=lane&31 (query), row = (i&3) + 8*(i>>2) + 4*kh.  Verified rounds 3-18.
__device__ __forceinline__ void load_atile(const _Float16* __restrict__ xh,
                                           const _Float16* __restrict__ xl,
                                           int b, int ptile, int lane,
                                           f16x8* Ah, f16x8* Al) {
#pragma unroll
    for (int t = 0; t < 4; ++t) {
        size_t o = frag_off(b, ptile, t, lane);
        Ah[t] = *(const f16x8*)&xh[o];   // coalesced: 64 lanes x 16 B contiguous
        Al[t] = *(const f16x8*)&xl[o];
    }
}

// r22: sqs holds -sq/2 (pre-scaled at staging). c0 is INITIALIZED from sqs, so the
// MFMA chain computes -sq/2 + dot_hi directly. Shared by kT and kS -> d stays
// bitwise-identical across both kernels (the kM2 threshold invariant).
__device__ __forceinline__ void dist_from_frags(const f16x8* Ah, const f16x8* Al,
                                                const float* sqs, int sbase, int kh,
                                                const f16x8* Qh, const f16x8* Ql,
                                                float* dv) {
    f32x16 c0, c1;
#pragma unroll
    for (int r2 = 0; r2 < 4; ++r2) {
        float4 sv = *(const float4*)&sqs[sbase + 8 * r2 + 4 * kh];  // -sq/2, LDS broadcast
        c0[4 * r2 + 0] = sv.x;
        c0[4 * r2 + 1] = sv.y;
        c0[4 * r2 + 2] = sv.z;
        c0[4 * r2 + 3] = sv.w;
    }
#pragma unroll
    for (int i = 0; i < 16; ++i) c1[i] = 0.f;
#pragma unroll
    for (int t = 0; t < 4; ++t) {
        c0 = __builtin_amdgcn_mfma_f32_32x32x16_f16(Ah[t], Qh[t], c0, 0, 0, 0); // -sq/2 + hi*hi
        c1 = __builtin_amdgcn_mfma_f32_32x32x16_f16(Ah[t], Ql[t], c1, 0, 0, 0); // hi*lo
        c1 = __builtin_amdgcn_mfma_f32_32x32x16_f16(Al[t], Qh[t], c1, 0, 0, 0); // lo*hi
    }
#pragma unroll
    for (int i = 0; i < 16; ++i)
        dv[i] = fmaf(-2.f, c0[i], -9.765625e-4f * c1[i]);  // d = sq - 2dot - cross
}

__device__ __forceinline__ void load_qfrag(const _Float16* __restrict__ xh,
                                           const _Float16* __restrict__ xl,
                                           int b, int qbase, int lane,
                                           f16x8* Qh, f16x8* Ql) {
    const int qtile = qbase >> 5;
#pragma unroll
    for (int t = 0; t < 4; ++t) {
        size_t o = frag_off(b, qtile, t, lane);
        Qh[t] = *(const f16x8*)&xh[o];
        Ql[t] = *(const f16x8*)&xl[o];
    }
}

// ---------------- kernel A: sq + fp16 hi/lo split (swizzled) + y1/y2 ----------------
// r17 structure: x staged in LDS once; o-split into 2 groups of 32.
__global__ void __launch_bounds__(256, 2)
kA(const float* __restrict__ x, const float* __restrict__ W,
   float* __restrict__ ws) {
    __shared__ __align__(16) float w1s[32 * 64];   // 8 KB: this block's 32 o rows
    __shared__ __align__(16) float w2s[32 * 64];   // 8 KB
    __shared__ float xs[64 * 65];                  // 16.6 KB [c][n], pad 65
    __shared__ float tb[64 * 33];                  // 8.4 KB transpose, pad 33
    const int bb = blockIdx.z;
    const int og = blockIdx.y;        // o-group: 0 or 1
    const int obase = og * 32;
    const int nbase = blockIdx.x * 64;
    const int tn = threadIdx.x & 63, tq = threadIdx.x >> 6;

    // W slice (32 o x 64 c), w2 = W_right - W_left
    for (int i = threadIdx.x; i < 2048; i += 256) {
        int ol = i >> 6, c = i & 63;
        float a = W[(obase + ol) * 128 + c];
        float d = W[(obase + ol) * 128 + 64 + c];
        w1s[i] = a;
        w2s[i] = d - a;
    }
    // x tile: [c][n] staged coalesced (256 B per row-segment)
    for (int i = threadIdx.x; i < 4096; i += 256) {
        int c = i >> 6, nl = i & 63;
        xs[c * 65 + nl] = x[((size_t)bb * 64 + c) * NN + nbase + nl];
    }
    if (og == 0) {
        if (blockIdx.x == 0 && bb == 0 && threadIdx.x < 128)
            ws[ST_OFF + threadIdx.x] = 0.f;   // zero stats accumulators (pre-kC1)
        int gid = (bb * 128 + blockIdx.x) * 256 + threadIdx.x;  // init cnt (pre-kS)
        if (gid < BB * NN) ((int*)(ws + CN_OFF))[gid] = 0;
    }
    __syncthreads();

    // per-thread column n = tn (conflict-free: bank = (c+tn)%32)
    float xc[64];
#pragma unroll
    for (int c = 0; c < 64; ++c) xc[c] = xs[c * 65 + tn];

    if (og == 0 && tq == 0) {   // sq + swizzled fp16 split (one wave, per-n)
        float sqv = 0.f;
#pragma unroll
        for (int c = 0; c < 64; ++c) sqv = fmaf(xc[c], xc[c], sqv);
        int n = nbase + tn;
        ws[SQ_OFF + (size_t)bb * NN + n] = sqv;
        _Float16* xh = (_Float16*)(ws + XH_OFF);
        _Float16* xl = (_Float16*)(ws + XL_OFF);
        int tile = n >> 5, r = n & 31;
#pragma unroll
        for (int t = 0; t < 4; ++t) {
#pragma unroll
            for (int kh = 0; kh < 2; ++kh) {
                f16x8 vh, vl;
#pragma unroll
                for (int j = 0; j < 8; ++j) {
                    float v = xc[t * 16 + kh * 8 + j];
                    _Float16 h = (_Float16)v;
                    vh[j] = h;
                    vl[j] = (_Float16)((v - (float)h) * 2048.f);  // x = hi + lo*2^-11
                }
                size_t o = frag_off(bb, tile, t, kh * 32 + r);    // lane-consecutive
                *(f16x8*)&xh[o] = vh;
                *(f16x8*)&xl[o] = vl;
            }
        }
    }

    // projections: thread = n, 8 o's each (o_local = tq*8 + o2)
    float a1v[8], a2v[8];
#pragma unroll
    for (int o2 = 0; o2 < 8; ++o2) {
        int ol = tq * 8 + o2;
        const float4* w1v = (const float4*)&w1s[ol * 64];
        const float4* w2v = (const float4*)&w2s[ol * 64];
        float a1 = 0.f, a2 = 0.f;
#pragma unroll
        for (int c4 = 0; c4 < 16; ++c4) {
            float4 v1 = w1v[c4];   // broadcast ds_read_b128
            float4 v2 = w2v[c4];
            a1 = fmaf(v1.x, xc[4*c4],   a1);
            a1 = fmaf(v1.y, xc[4*c4+1], a1);
            a1 = fmaf(v1.z, xc[4*c4+2], a1);
            a1 = fmaf(v1.w, xc[4*c4+3], a1);
            a2 = fmaf(v2.x, xc[4*c4],   a2);
            a2 = fmaf(v2.y, xc[4*c4+1], a2);
            a2 = fmaf(v2.z, xc[4*c4+2], a2);
            a2 = fmaf(v2.w, xc[4*c4+3], a2);
        }
        a1v[o2] = a1;
        a2v[o2] = a2;
    }

    // y1: transpose through tb, then full-line stores (2 rows x 128 B per instr)
    const int lo = threadIdx.x & 31;          // o_local
    const int lp = (threadIdx.x >> 5) & 1;    // row parity
#pragma unroll
    for (int o2 = 0; o2 < 8; ++o2)
        tb[tn * 33 + tq * 8 + o2] = a1v[o2];
    __syncthreads();
#pragma unroll
    for (int j = 0; j < 8; ++j) {
        int r = tq * 16 + 2 * j + lp;
        ws[Y1_OFF + ((size_t)bb * NN + nbase + r) * 64 + obase + lo] = tb[r * 33 + lo];
    }
    __syncthreads();
#pragma unroll
    for (int o2 = 0; o2 < 8; ++o2)
        tb[tn * 33 + tq * 8 + o2] = a2v[o2];
    __syncthreads();
#pragma unroll
    for (int j = 0; j < 8; ++j) {
        int r = tq * 16 + 2 * j + lp;
        ws[Y2_OFF + ((size_t)bb * NN + nbase + r) * 64 + obase + lo] = tb[r * 33 + lo];
    }
}

// ---------------- kernel T (phase-0): half-sample top-20 lists, branchless networks ----------------
__global__ void __launch_bounds__(256, 3)
kT(const _Float16* __restrict__ xh, const _Float16* __restrict__ xl,
   const float* __restrict__ sq, float* __restrict__ thrL) {
    __shared__ float mrg[32 * 128];          // [j][wave*32+qc]
    __shared__ __align__(16) float sqs[1024];  // staged -sq/2 slice (lgkmcnt path)
    const int tid  = threadIdx.x;
    const int lane = tid & 63;
    const int wv   = tid >> 6;
    const int qcol = lane & 31;
    const int kh   = lane >> 5;
    const int b     = blockIdx.y >> 1;
    const int s     = blockIdx.y & 1;     // sample half
    const int qbase = blockIdx.x * 32;

    for (int i = tid; i < 1024; i += 256)
        sqs[i] = -0.5f * sq[(size_t)b * NN + s * 1024 + i];   // r22: pre-scaled

    f16x8 Qh[4], Ql[4];
    load_qfrag(xh, xl, b, qbase, lane, Qh, Ql);
    __syncthreads();

    float dk[32];
#pragma unroll
    for (int i = 0; i < 32; ++i) dk[i] = FLT_MAX;

    const int p0 = s * 1024 + wv * 256;
    for (int pt = p0; pt < p0 + 256; pt += 32) {
        f16x8 Ah[4], Al[4];
        load_atile(xh, xl, b, pt >> 5, lane, Ah, Al);
        float dv[16];
        dist_from_frags(Ah, Al, sqs, pt - s * 1024, kh, Qh, Ql, dv);
        float m16 = dv[0];
#pragma unroll
        for (int i = 1; i < 16; ++i) m16 = fminf(m16, dv[i]);
        if (__any(m16 < dk[KK - 1])) {   // wave-uniform tile skip (late tiles)
            sort16(dv);
            merge32_16(dk, dv);
        }
    }

    // kh pair merge via shfl (branchless; kh==1 lanes self-merge harmlessly)
    {
        float B[32];
#pragma unroll
        for (int j = 0; j < 32; ++j) B[j] = __shfl(dk[j], lane | 32);
        merge32_32(dk, B);
    }
    if (kh == 0) {
#pragma unroll
        for (int j = 0; j < 32; ++j) mrg[j * 128 + wv * 32 + qcol] = dk[j];
    }
    __syncthreads();

    // cross-wave merge: wave 0, lanes 0-31, one query per lane; emit sorted 20-list
    if (tid < 32) {
        float B[32];
#pragma unroll 1
        for (int w = 1; w < 4; ++w) {
#pragma unroll
            for (int j = 0; j < 32; ++j) B[j] = mrg[j * 128 + w * 32 + tid];
            merge32_32(dk, B);
        }
        size_t base = (((size_t)b * 2 + s) * NN + qbase + tid) * KK;
#pragma unroll
        for (int j = 0; j < KK; ++j) thrL[base + j] = dk[j];
    }
}

// ---------------- kernel M2: exact union 20th via k-th-of-two-sorted identity ----------------
// r18-keep: ans = min_{i} max(A[i-1], B[19-i]) -- 10 independent float4 loads.
__global__ void kM2(const float* __restrict__ thrL, float* __restrict__ thr) {
    int gid = blockIdx.x * 256 + threadIdx.x;      // 0 .. B*N-1
    int b = gid >> 13, q = gid & (NN - 1);
    float A[KK], Bv[KK];
    const float4* pa = (const float4*)&thrL[(((size_t)b * 2 + 0) * NN + q) * KK];
    const float4* pb = (const float4*)&thrL[(((size_t)b * 2 + 1) * NN + q) * KK];
#pragma unroll
    for (int i = 0; i < 5; ++i) {
        float4 va = pa[i];
        float4 vb = pb[i];
        A[4*i] = va.x;  A[4*i+1] = va.y;  A[4*i+2] = va.z;  A[4*i+3] = va.w;
        Bv[4*i] = vb.x; Bv[4*i+1] = vb.y; Bv[4*i+2] = vb.z; Bv[4*i+3] = vb.w;
    }
    float v = fminf(Bv[KK - 1], A[KK - 1]);        // i=0 and i=20 boundary terms
#pragma unroll
    for (int i = 1; i < KK; ++i)
        v = fminf(v, fmaxf(A[i - 1], Bv[KK - 1 - i]));
    // kT/kS share bitwise-identical d; tiny inflation is pure safety margin
    thr[gid] = v + fabsf(v) * 1e-6f + 1e-6f;
}

// ---------------- kernel S (phase-1): barrier-free register-direct sweep ----------------
// Proven r22/r5 form: lbuf batched emit, MS=16/CHUNK=512, bounds(256,4), ~75 us.
__global__ void __launch_bounds__(256, 4)
kS(const _Float16* __restrict__ xh, const _Float16* __restrict__ xl,
   const float* __restrict__ sq, const float* __restrict__ thr,
   int* __restrict__ cnt, u64* __restrict__ cand) {
    __shared__ u64 lbuf[256 * RBS];                // 18 KB (odd stride: conflict-free)
    __shared__ __align__(16) float sqs[CHUNK];     // 2 KB, holds -sq/2
    const int tid  = threadIdx.x;
    const int lane = tid & 63;
    const int wv   = tid >> 6;
    const int qcol = lane & 31;
    const int kh   = lane >> 5;
    const int id     = blockIdx.x;        // 2048 = 16 chunk x 64 qtile x 2 b
    const int ychunk = id & 15;           // chunk c -> XCD c&7 (2 chunks/XCD in L2)
    const int qt     = (id >> 4) & 63;
    const int b      = (id >> 10) & 1;
    const int qbase  = qt * QB + wv * 32;
    const int pbase0 = ychunk * CHUNK;
    const int ptile0 = pbase0 >> 5;

    for (int i = tid; i < CHUNK; i += 256)
        sqs[i] = -0.5f * sq[(size_t)b * NN + pbase0 + i];   // r22: pre-scaled

    f16x8 Qh[4], Ql[4];
    load_qfrag(xh, xl, b, qbase, lane, Qh, Ql);

    const size_t qidx = (size_t)b * NN + qbase + qcol;
    const float tv = thr[qidx];
    const size_t cb = qidx * CAPQ;
    int c_ = 0;

    __syncthreads();   // sqs visible; the ONLY barrier in this kernel

    // one atomic per flush (normally once per lane, at the end)
    auto flushS = [&]() {
        if (c_ > 0) {
            int base = atomicAdd(&cnt[qidx], c_);
#pragma unroll 1
            for (int j = 0; j < c_; ++j) {
                int slot = base + j;
                if (slot < CAPQ) cand[cb + slot] = lbuf[tid * RBS + j];
            }
            c_ = 0;
        }
    };

#pragma unroll 2
    for (int tt = 0; tt < CHUNK / 32; ++tt) {
        f16x8 Ah[4], Al[4];
        load_atile(xh, xl, b, ptile0 + tt, lane, Ah, Al);   // global->reg, L1/L2-hot
        float dv[16];
        dist_from_frags(Ah, Al, sqs, tt * 32, kh, Qh, Ql, dv);

        const int pb4 = pbase0 + tt * 32 + 4 * kh;
#pragma unroll
        for (int i = 0; i < 16; ++i) {
            float d = dv[i];
            if (d <= tv) {                           // rare (~1% of pairs)
                int id2 = pb4 + ((i & 3) + 8 * (i >> 2));
                lbuf[tid * RBS + c_] = ((u64)fmap(d) << 32) | (unsigned)id2;
                if (++c_ == RB) flushS();            // exact, rare overflow guard
            }
        }
    }
    flushS();
}

// ---------------- kernel P (phase-2): exact top-K via RANK SELECTION ----------------
// r28: insertion-sort kP stuck at ~53 us across two designs (r7: 48 us / 2-lane;
// r10: ~53 us inferred / 8-lane no-break) -- the kk[20] insU-chain structure is the
// problem (spill and/or wave-wide divergent chain execution). Replace the algorithm:
// keys are UNIQUE u64 (low 32 bits = idx), so top-20 = keys with rank < 20 where
// rank = #keys strictly smaller. One WAVE per query: lane holds 3 keys (slots
// lane, lane+64, lane+128 -- fully COALESCED 512B loads), loop j=0..m-1 broadcasting
// key j via shfl (v0/v1/v2 statically selected), 3 scalar rank counters per lane.
// Ranks unique 0..m-1; m >= 20 guaranteed (thr >= exact 20th + eps). Write
// op[rank]=idx for rank<20: same ascending order, bitwise-identical output.
// State = 3 u64 + 3 ints -> spill impossible. ~650 wave-insts, BW-bound loads.
__global__ void __launch_bounds__(256, 4)
kP(const int* __restrict__ cnt, const u64* __restrict__ cand,
   int* __restrict__ idxK) {
    const int lane = threadIdx.x & 63;
    const int wq   = threadIdx.x >> 6;               // query within block (4 waves)
    const int q    = blockIdx.x * 4 + wq;
    int m = cnt[q];
    m = m < CAPQ ? m : CAPQ;
    const u64* cp = &cand[(size_t)q * CAPQ];

    // held keys: slots lane, lane+64, lane+128 (3 coalesced 512B wave-loads)
    u64 v0 = (lane       < m) ? cp[lane]       : ~0ull;
    u64 v1 = (lane + 64  < m) ? cp[lane + 64]  : ~0ull;
    u64 v2 = (lane + 128 < m) ? cp[lane + 128] : ~0ull;
    int r0 = 0, r1 = 0, r2 = 0;

    // rank = #keys strictly smaller (self-compare contributes 0; invalid = ~0ull
    // never counted as smaller and never broadcast). m is wave-uniform.
    {
        const int cap0 = m < 64 ? m : 64;
#pragma unroll 4
        for (int jj = 0; jj < cap0; ++jj) {
            u64 bv = __shfl(v0, jj);
            r0 += (bv < v0); r1 += (bv < v1); r2 += (bv < v2);
        }
    }
    if (m > 64) {
        const int cap1 = (m - 64) < 64 ? (m - 64) : 64;
#pragma unroll 4
        for (int jj = 0; jj < cap1; ++jj) {
            u64 bv = __shfl(v1, jj);
            r0 += (bv < v0); r1 += (bv < v1); r2 += (bv < v2);
        }
    }
    if (m > 128) {
        const int cap2 = (m - 128) < 64 ? (m - 128) : 64;
#pragma unroll 4
        for (int jj = 0; jj < cap2; ++jj) {
            u64 bv = __shfl(v2, jj);
            r0 += (bv < v0); r1 += (bv < v1); r2 += (bv < v2);
        }
    }

    int* op = &idxK[(size_t)q * KK];
    if (lane       < m && r0 < KK) op[r0] = (int)(unsigned)(v0 & 0xffffffffu);
    if (lane + 64  < m && r1 < KK) op[r1] = (int)(unsigned)(v1 & 0xffffffffu);
    if (lane + 128 < m && r2 < KK) op[r2] = (int)(unsigned)(v2 & 0xffffffffu);
}

// ---------------- kernel C1: gather + stats + hmax/hmin (o-major out, r17 form) ----------------
__global__ void kC1(const float* __restrict__ y1, const float* __restrict__ y2,
                    const int* __restrict__ idxK, float* __restrict__ hmaxT,
                    float* __restrict__ hminT, float* __restrict__ stats) {
    __shared__ int li[32 * KK];          // all 640 neighbor indices, staged once
    __shared__ float red[256];
    __shared__ float thm[32 * 65];       // [n_local][o], pad 65 -> conflict-free
    __shared__ float thn[32 * 65];
    int b = blockIdx.y;
    int o = threadIdx.x & 63;
    int nn = threadIdx.x >> 6;
    int nbase = blockIdx.x * 32;

    for (int i = threadIdx.x; i < 32 * KK; i += 256)
        li[i] = idxK[((size_t)b * NN + nbase) * KK + i];
    __syncthreads();

    float s = 0.f, ss = 0.f;
    for (int gidx = 0; gidx < 8; ++gidx) {
        int nl = gidx * 4 + nn;
        int n = nbase + nl;
        float y2v = y2[((size_t)b * NN + n) * 64 + o];
        float hm = -FLT_MAX, hn = FLT_MAX;
        const int* lin = &li[nl * KK];
#pragma unroll 4
        for (int k = 0; k < KK; ++k) {
            int j = lin[k];            // wave-uniform (nn fixed per wave)
            float h = y1[((size_t)b * NN + j) * 64 + o] + y2v;   // coalesced 256B, L2-hot
            s += h;
            ss += h * h;
            hm = fmaxf(hm, h);
            hn = fminf(hn, h);
        }
        thm[nl * 65 + o] = hm;
        thn[nl * 65 + o] = hn;
    }
    __syncthreads();

    // transposed store: 8 half-wave groups, each writes 8 o-rows
    int l = threadIdx.x & 31, g = threadIdx.x >> 5;
#pragma unroll
    for (int i = 0; i < 8; ++i) {
        int o2 = g * 8 + i;
        hmaxT[((size_t)b * 64 + o2) * NN + nbase + l] = thm[l * 65 + o2];
        hminT[((size_t)b * 64 + o2) * NN + nbase + l] = thn[l * 65 + o2];
    }

    __syncthreads();
    red[threadIdx.x] = s;
    __syncthreads();
    if (threadIdx.x < 64) {
        float v = red[o] + red[64 + o] + red[128 + o] + red[192 + o];
        atomicAdd(&stats[o], v);
    }
    __syncthreads();
    red[threadIdx.x] = ss;
    __syncthreads();
    if (threadIdx.x < 64) {
        float v = red[o] + red[64 + o] + red[128 + o] + red[192 + o];
        atomicAdd(&stats[64 + o], v);
    }
}

// ---------------- kernel C3: finalize BN + leaky + max-over-k (all coalesced) ----------------
__global__ void kC3(const float* __restrict__ hmaxT, const float* __restrict__ hminT,
                    const float* __restrict__ stats, const float* __restrict__ gamma,
                    const float* __restrict__ beta, float* __restrict__ out) {
    int o = blockIdx.x;
    int half = blockIdx.y;
    int b = blockIdx.z;
    const float c = (float)BB * NN * KK;
    float mean = stats[o] / c;
    float var = stats[64 + o] / c - mean * mean;
    float rs = rsqrtf(var + 1e-5f);
    float a = gamma[o] * rs;
    float b2 = beta[o] - a * mean;
    size_t rowb = ((size_t)b * 64 + o) * NN;
    int n0 = half * (NN / 2), n1 = n0 + NN / 2;
    for (int n = n0 + threadIdx.x; n < n1; n += 256) {
        float hm = hmaxT[rowb + n];    // coalesced
        float hn = hminT[rowb + n];
        float hs = (a >= 0.f) ? hm : hn;   // affine monotone: max or min per sign of a
        float v = a * hs + b2;
        v = (v >= 0.f) ? v : 0.2f * v;
        out[rowb + n] = v;             // coalesced
    }
}

extern "C" void kernel_launch(void* const* d_in, const int* in_sizes, int n_in,
                              void* d_out, int out_size, void* d_ws, size_t ws_size,
                              hipStream_t stream) {
    const float* x     = (const float*)d_in[0];
    const float* W     = (const float*)d_in[1];
    const float* gamma = (const float*)d_in[2];
    const float* beta  = (const float*)d_in[3];
    float* out = (float*)d_out;
    float* ws  = (float*)d_ws;

    _Float16* xh = (_Float16*)(ws + XH_OFF);
    _Float16* xl = (_Float16*)(ws + XL_OFF);
    float* sq    = ws + SQ_OFF;
    float* y1    = ws + Y1_OFF;
    float* y2    = ws + Y2_OFF;
    float* thr   = ws + TH_OFF;
    int*   cnt   = (int*)(ws + CN_OFF);
    float* thrL  = ws + TL_OFF;
    u64*   cand  = (u64*)(ws + CA_OFF);
    int*   idxK  = (int*)(ws + IX_OFF);
    float* hmaxT = ws + HX_OFF;
    float* hminT = ws + HN_OFF;
    float* stats = ws + ST_OFF;

    kA<<<dim3(NN / 64, 2, BB), 256, 0, stream>>>(x, W, ws);
    kT<<<dim3(NN / 32, 2 * BB), 256, 0, stream>>>(xh, xl, sq, thrL);
    kM2<<<dim3(BB * NN / 256), 256, 0, stream>>>(thrL, thr);
    kS<<<dim3(MS * (NN / QB) * BB), 256, 0, stream>>>(xh, xl, sq, thr, cnt, cand);
    kP<<<dim3(BB * NN / 4), 256, 0, stream>>>(cnt, cand, idxK);
    kC1<<<dim3(NN / 32, BB), 256, 0, stream>>>(y1, y2, idxK, hmaxT, hminT, stats);
    kC3<<<dim3(OO, 2, BB), 256, 0, stream>>>(hmaxT, hminT, stats, gamma, beta, out);
}